// Round 3
// baseline (203.712 us; speedup 1.0000x reference)
//
#include <hip/hip_runtime.h>
#include <hip/hip_bf16.h>

#define B_    32
#define CDD_  5
#define HIS_  50
#define L_    32
#define LVL_  2
#define H_    256
#define K_    5
#define NCDD  (B_*CDD_)        // 160
#define NHIS  (B_*HIS_)        // 1600
#define NROWS (NCDD + NHIS)    // 1760
#define SLAB  (L_*LVL_*H_)     // 16384 floats per (b,his) embedding slab
#define OUT0  ((size_t)NCDD*K_*SLAB)  // 13,107,200 floats

typedef float f32x4 __attribute__((ext_vector_type(4)));  // native vec for NT builtins

// ---------------------------------------------------------------------------
// Kernel 0: WT[k][t] = W[t][k]  (64x64 LDS tiles, 16 blocks)
// ---------------------------------------------------------------------------
__global__ __launch_bounds__(256) void transpose_w_kernel(
    const float* __restrict__ Wm, float* __restrict__ WT)
{
    __shared__ float tile[64][65];
    const int tx = threadIdx.x & 63, ty = threadIdx.x >> 6;
    const int c0 = (blockIdx.x & 3) * 64, r0 = (blockIdx.x >> 2) * 64;
    #pragma unroll
    for (int i = 0; i < 16; ++i)
        tile[ty + i*4][tx] = Wm[(size_t)(r0 + ty + i*4) * H_ + c0 + tx];
    __syncthreads();
    #pragma unroll
    for (int i = 0; i < 16; ++i)
        WT[(size_t)(c0 + ty + i*4) * H_ + r0 + tx] = tile[tx][ty + i*4];
}

// ---------------------------------------------------------------------------
// Kernel A: Y[r] = l2norm(x_r @ W^T + b), outer-product form with WT.
// 8 rows/block (220 blocks). Wave g handles rows r0+2g..r0+2g+1, lane handles
// cols 4*lane..4*lane+3. Per k: one coalesced float4 of WT row + LDS
// broadcasts of x. Row norm reduces fully within one wave (xor shuffle).
// ---------------------------------------------------------------------------
__global__ __launch_bounds__(256) void proj_norm_kernel(
    const float* __restrict__ cdd, const float* __restrict__ his,
    const float* __restrict__ WT, const float* __restrict__ bias,
    float* __restrict__ Y)
{
    __shared__ float xs[8][H_];
    const int t = threadIdx.x;
    const int r0 = blockIdx.x * 8;
    const int wave = t >> 6, lane = t & 63;

    // stage 8 input rows, coalesced float4 (512 float4 over 256 threads)
    #pragma unroll
    for (int j = t; j < 8 * H_ / 4; j += 256) {
        int rr = j >> 6, cc = j & 63;
        int row = r0 + rr;
        const float* src = (row < NCDD) ? (cdd + (size_t)row * H_)
                                        : (his + (size_t)(row - NCDD) * H_);
        ((float4*)xs[rr])[cc] = ((const float4*)src)[cc];
    }
    __syncthreads();

    const int ra = 2 * wave, rb = ra + 1;
    float4 a0 = {0,0,0,0}, a1 = {0,0,0,0};
    #pragma unroll 4
    for (int k = 0; k < H_; ++k) {
        float4 wv = ((const float4*)(WT + (size_t)k * H_))[lane];
        float x0 = xs[ra][k], x1 = xs[rb][k];
        a0.x = fmaf(x0, wv.x, a0.x); a0.y = fmaf(x0, wv.y, a0.y);
        a0.z = fmaf(x0, wv.z, a0.z); a0.w = fmaf(x0, wv.w, a0.w);
        a1.x = fmaf(x1, wv.x, a1.x); a1.y = fmaf(x1, wv.y, a1.y);
        a1.z = fmaf(x1, wv.z, a1.z); a1.w = fmaf(x1, wv.w, a1.w);
    }
    float4 bv = ((const float4*)bias)[lane];
    a0.x += bv.x; a0.y += bv.y; a0.z += bv.z; a0.w += bv.w;
    a1.x += bv.x; a1.y += bv.y; a1.z += bv.z; a1.w += bv.w;

    float s0 = a0.x*a0.x + a0.y*a0.y + a0.z*a0.z + a0.w*a0.w;
    float s1 = a1.x*a1.x + a1.y*a1.y + a1.z*a1.z + a1.w*a1.w;
    #pragma unroll
    for (int off = 1; off < 64; off <<= 1) {
        s0 += __shfl_xor(s0, off);
        s1 += __shfl_xor(s1, off);
    }
    float i0 = 1.0f / fmaxf(sqrtf(s0), 1e-12f);
    float i1 = 1.0f / fmaxf(sqrtf(s1), 1e-12f);
    a0.x *= i0; a0.y *= i0; a0.z *= i0; a0.w *= i0;
    a1.x *= i1; a1.y *= i1; a1.z *= i1; a1.w *= i1;

    ((float4*)(Y + (size_t)(r0 + ra) * H_))[lane] = a0;
    ((float4*)(Y + (size_t)(r0 + rb) * H_))[lane] = a1;
}

// ---------------------------------------------------------------------------
// Kernel B: per (b,cdd): 50 cosine scores, top-5 (desc, first-index ties),
// threshold weights, write idx/w to ws and the mask output (as float).
// ---------------------------------------------------------------------------
__global__ __launch_bounds__(256) void attn_topk_kernel(
    const float* __restrict__ Y, const int* __restrict__ mask,
    int* __restrict__ idx_ws, float* __restrict__ w_ws,
    float* __restrict__ mask_out)
{
    const int bc = blockIdx.x;          // 0..159  (= b*CDD + cd)
    const int b  = bc / CDD_;
    __shared__ float cs[H_];
    __shared__ float scores[HIS_];
    __shared__ int   sidx[K_];
    const int t = threadIdx.x;

    cs[t] = Y[(size_t)bc * H_ + t];     // cdd rows occupy Y[0..160)
    __syncthreads();

    const int wave = t >> 6, lane = t & 63;
    for (int h = wave; h < HIS_; h += 4) {
        const float4* hv = (const float4*)(Y + (size_t)(NCDD + b * HIS_ + h) * H_);
        float4 x  = hv[lane];
        float4 c4 = ((float4*)cs)[lane];
        float p = x.x*c4.x + x.y*c4.y + x.z*c4.z + x.w*c4.w;
        #pragma unroll
        for (int off = 32; off; off >>= 1) p += __shfl_down(p, off);
        if (lane == 0) scores[h] = p;
    }
    __syncthreads();

    if (t == 0) {
        #pragma unroll
        for (int k = 0; k < K_; ++k) {
            float best = -1e30f; int bi = 0;
            for (int h = 0; h < HIS_; ++h)
                if (scores[h] > best) { best = scores[h]; bi = h; }  // ties -> first
            scores[bi] = -1e30f;
            sidx[k] = bi;
            idx_ws[bc * K_ + k] = bi;
            w_ws[bc * K_ + k]   = (best < 0.1f) ? 0.0f : best;
        }
    }
    __syncthreads();

    if (t < K_ * L_) {
        int k = t / L_, l = t % L_;
        mask_out[((size_t)bc * K_ + k) * L_ + l] =
            (float)mask[((size_t)(b * HIS_ + sidx[k])) * L_ + l];
    }
}

// ---------------------------------------------------------------------------
// Kernel C: out0[(bc,k)] = emb[b, idx[bc,k]] * w[bc,k].
// 4 blocks per slab (3200 blocks); 4 float4/thread. If w==0 the result is
// exactly zero -> skip the 64KB read entirely. Nontemporal stores (no reuse).
// ---------------------------------------------------------------------------
__global__ __launch_bounds__(256) void gather_scale_kernel(
    const float* __restrict__ emb, const int* __restrict__ idx_ws,
    const float* __restrict__ w_ws, float* __restrict__ out)
{
    const int gb   = blockIdx.x;
    const int part = gb & 3;            // quarter of a slab (1024 float4)
    const int bck  = gb >> 2;           // 0..799 (= bc*K + k)
    const int bc   = bck / K_;
    const int b    = bc / CDD_;
    const float w  = w_ws[bck];

    f32x4* dst = (f32x4*)((float4*)(out + (size_t)bck * SLAB) + part * 1024 + threadIdx.x);

    if (w == 0.0f) {
        f32x4 z = {0.f, 0.f, 0.f, 0.f};
        #pragma unroll
        for (int j = 0; j < 4; ++j)
            __builtin_nontemporal_store(z, dst + j * 256);
    } else {
        const int i = idx_ws[bck];
        const f32x4* src = (const f32x4*)((const float4*)(emb + (size_t)(b * HIS_ + i) * SLAB)
                          + part * 1024 + threadIdx.x);
        f32x4 v[4];
        #pragma unroll
        for (int j = 0; j < 4; ++j) v[j] = src[j * 256];
        #pragma unroll
        for (int j = 0; j < 4; ++j) {
            v[j] *= w;
            __builtin_nontemporal_store(v[j], dst + j * 256);
        }
    }
}

// ---------------------------------------------------------------------------
extern "C" void kernel_launch(void* const* d_in, const int* in_sizes, int n_in,
                              void* d_out, int out_size, void* d_ws, size_t ws_size,
                              hipStream_t stream) {
    const float* cdd  = (const float*)d_in[0];
    const float* his  = (const float*)d_in[1];
    const float* emb  = (const float*)d_in[2];
    const int*   mask = (const int*)  d_in[3];
    const float* Wm   = (const float*)d_in[4];
    const float* bias = (const float*)d_in[5];
    float* out = (float*)d_out;

    // workspace layout
    float* WT     = (float*)d_ws;                                   // 256*256 f32
    float* Y      = WT + (size_t)H_ * H_;                           // 1760*256 f32
    int*   idx_ws = (int*)(Y + (size_t)NROWS * H_);                 // 800 i32
    float* w_ws   = (float*)(idx_ws + NCDD * K_);                   // 800 f32

    transpose_w_kernel<<<16, 256, 0, stream>>>(Wm, WT);
    proj_norm_kernel<<<NROWS / 8, 256, 0, stream>>>(cdd, his, WT, bias, Y);
    attn_topk_kernel<<<NCDD, 256, 0, stream>>>(Y, mask, idx_ws, w_ws, out + OUT0);
    gather_scale_kernel<<<NCDD * K_ * 4, 256, 0, stream>>>(emb, idx_ws, w_ws, out);
}

// Round 4
// 199.830 us; speedup vs baseline: 1.0194x; 1.0194x over previous
//
#include <hip/hip_runtime.h>
#include <hip/hip_bf16.h>

#define B_    32
#define CDD_  5
#define HIS_  50
#define L_    32
#define LVL_  2
#define H_    256
#define K_    5
#define NCDD  (B_*CDD_)        // 160
#define NHIS  (B_*HIS_)        // 1600
#define NROWS (NCDD + NHIS)    // 1760
#define SLAB  (L_*LVL_*H_)     // 16384 floats per (b,his) embedding slab
#define OUT0  ((size_t)NCDD*K_*SLAB)  // 13,107,200 floats

typedef float f32x4 __attribute__((ext_vector_type(4)));  // native vec for NT builtins

// ---------------------------------------------------------------------------
// Kernel 0: WT[k][t] = W[t][k]  (64x64 LDS tiles, 16 blocks)
// ---------------------------------------------------------------------------
__global__ __launch_bounds__(256) void transpose_w_kernel(
    const float* __restrict__ Wm, float* __restrict__ WT)
{
    __shared__ float tile[64][65];
    const int tx = threadIdx.x & 63, ty = threadIdx.x >> 6;
    const int c0 = (blockIdx.x & 3) * 64, r0 = (blockIdx.x >> 2) * 64;
    #pragma unroll
    for (int i = 0; i < 16; ++i)
        tile[ty + i*4][tx] = Wm[(size_t)(r0 + ty + i*4) * H_ + c0 + tx];
    __syncthreads();
    #pragma unroll
    for (int i = 0; i < 16; ++i)
        WT[(size_t)(c0 + ty + i*4) * H_ + r0 + tx] = tile[tx][ty + i*4];
}

// ---------------------------------------------------------------------------
// Kernel A: Y[r] = l2norm(x_r @ W^T + b), outer-product form with WT.
// 4 rows/block (440 blocks, ~7 waves/CU for latency hiding). One row per
// wave; lane owns cols 4*lane..4*lane+3. Per k: one coalesced float4 of the
// WT row (L2-resident, 256 KB) + an LDS broadcast of x[k] (same addr across
// wave = free). unroll 8 keeps 8 global loads in flight. Row norm reduces
// within the wave (xor shuffle).
// ---------------------------------------------------------------------------
__global__ __launch_bounds__(256) void proj_norm_kernel(
    const float* __restrict__ cdd, const float* __restrict__ his,
    const float* __restrict__ WT, const float* __restrict__ bias,
    float* __restrict__ Y)
{
    __shared__ float xs[4][H_];
    const int t = threadIdx.x;
    const int r0 = blockIdx.x * 4;
    const int wave = t >> 6, lane = t & 63;

    {   // stage 4 input rows, coalesced float4 (256 float4 over 256 threads)
        const int rr = wave, cc = lane;
        const int row = r0 + rr;
        const float* src = (row < NCDD) ? (cdd + (size_t)row * H_)
                                        : (his + (size_t)(row - NCDD) * H_);
        ((float4*)xs[rr])[cc] = ((const float4*)src)[cc];
    }
    float4 bv = ((const float4*)bias)[lane];   // overlap with barrier
    __syncthreads();

    const float* xrow = xs[wave];
    float4 a = {0.f, 0.f, 0.f, 0.f};
    #pragma unroll 8
    for (int k = 0; k < H_; ++k) {
        float4 wv = ((const float4*)(WT + (size_t)k * H_))[lane];
        float x = xrow[k];
        a.x = fmaf(x, wv.x, a.x);
        a.y = fmaf(x, wv.y, a.y);
        a.z = fmaf(x, wv.z, a.z);
        a.w = fmaf(x, wv.w, a.w);
    }
    a.x += bv.x; a.y += bv.y; a.z += bv.z; a.w += bv.w;

    float s = a.x*a.x + a.y*a.y + a.z*a.z + a.w*a.w;
    #pragma unroll
    for (int off = 1; off < 64; off <<= 1) s += __shfl_xor(s, off);
    const float inv = 1.0f / fmaxf(sqrtf(s), 1e-12f);   // matches F.normalize eps
    a.x *= inv; a.y *= inv; a.z *= inv; a.w *= inv;

    ((float4*)(Y + (size_t)(r0 + wave) * H_))[lane] = a;
}

// ---------------------------------------------------------------------------
// Kernel B: per (b,cdd): 50 cosine scores, top-5 (desc, first-index ties),
// threshold weights, write idx/w to ws and the mask output (as float).
// ---------------------------------------------------------------------------
__global__ __launch_bounds__(256) void attn_topk_kernel(
    const float* __restrict__ Y, const int* __restrict__ mask,
    int* __restrict__ idx_ws, float* __restrict__ w_ws,
    float* __restrict__ mask_out)
{
    const int bc = blockIdx.x;          // 0..159  (= b*CDD + cd)
    const int b  = bc / CDD_;
    __shared__ float cs[H_];
    __shared__ float scores[HIS_];
    __shared__ int   sidx[K_];
    const int t = threadIdx.x;

    cs[t] = Y[(size_t)bc * H_ + t];     // cdd rows occupy Y[0..160)
    __syncthreads();

    const int wave = t >> 6, lane = t & 63;
    for (int h = wave; h < HIS_; h += 4) {
        const float4* hv = (const float4*)(Y + (size_t)(NCDD + b * HIS_ + h) * H_);
        float4 x  = hv[lane];
        float4 c4 = ((float4*)cs)[lane];
        float p = x.x*c4.x + x.y*c4.y + x.z*c4.z + x.w*c4.w;
        #pragma unroll
        for (int off = 32; off; off >>= 1) p += __shfl_down(p, off);
        if (lane == 0) scores[h] = p;
    }
    __syncthreads();

    if (t == 0) {
        #pragma unroll
        for (int k = 0; k < K_; ++k) {
            float best = -1e30f; int bi = 0;
            for (int h = 0; h < HIS_; ++h)
                if (scores[h] > best) { best = scores[h]; bi = h; }  // ties -> first
            scores[bi] = -1e30f;
            sidx[k] = bi;
            idx_ws[bc * K_ + k] = bi;
            w_ws[bc * K_ + k]   = (best < 0.1f) ? 0.0f : best;
        }
    }
    __syncthreads();

    if (t < K_ * L_) {
        int k = t / L_, l = t % L_;
        mask_out[((size_t)bc * K_ + k) * L_ + l] =
            (float)mask[((size_t)(b * HIS_ + sidx[k])) * L_ + l];
    }
}

// ---------------------------------------------------------------------------
// Kernel C: out0[(bc,k)] = emb[b, idx[bc,k]] * w[bc,k].
// 4 blocks per slab (3200 blocks); 4 float4/thread. If w==0 the result is
// exactly zero -> skip the 64KB read entirely. Nontemporal stores (no reuse);
// normal loads so duplicate picks hit L2/L3.
// ---------------------------------------------------------------------------
__global__ __launch_bounds__(256) void gather_scale_kernel(
    const float* __restrict__ emb, const int* __restrict__ idx_ws,
    const float* __restrict__ w_ws, float* __restrict__ out)
{
    const int gb   = blockIdx.x;
    const int part = gb & 3;            // quarter of a slab (1024 float4)
    const int bck  = gb >> 2;           // 0..799 (= bc*K + k)
    const int bc   = bck / K_;
    const int b    = bc / CDD_;
    const float w  = w_ws[bck];

    f32x4* dst = (f32x4*)((float4*)(out + (size_t)bck * SLAB) + part * 1024 + threadIdx.x);

    if (w == 0.0f) {
        f32x4 z = {0.f, 0.f, 0.f, 0.f};
        #pragma unroll
        for (int j = 0; j < 4; ++j)
            __builtin_nontemporal_store(z, dst + j * 256);
    } else {
        const int i = idx_ws[bck];
        const f32x4* src = (const f32x4*)((const float4*)(emb + (size_t)(b * HIS_ + i) * SLAB)
                          + part * 1024 + threadIdx.x);
        f32x4 v[4];
        #pragma unroll
        for (int j = 0; j < 4; ++j) v[j] = src[j * 256];
        #pragma unroll
        for (int j = 0; j < 4; ++j) {
            v[j] *= w;
            __builtin_nontemporal_store(v[j], dst + j * 256);
        }
    }
}

// ---------------------------------------------------------------------------
extern "C" void kernel_launch(void* const* d_in, const int* in_sizes, int n_in,
                              void* d_out, int out_size, void* d_ws, size_t ws_size,
                              hipStream_t stream) {
    const float* cdd  = (const float*)d_in[0];
    const float* his  = (const float*)d_in[1];
    const float* emb  = (const float*)d_in[2];
    const int*   mask = (const int*)  d_in[3];
    const float* Wm   = (const float*)d_in[4];
    const float* bias = (const float*)d_in[5];
    float* out = (float*)d_out;

    // workspace layout
    float* WT     = (float*)d_ws;                                   // 256*256 f32
    float* Y      = WT + (size_t)H_ * H_;                           // 1760*256 f32
    int*   idx_ws = (int*)(Y + (size_t)NROWS * H_);                 // 800 i32
    float* w_ws   = (float*)(idx_ws + NCDD * K_);                   // 800 f32

    transpose_w_kernel<<<16, 256, 0, stream>>>(Wm, WT);
    proj_norm_kernel<<<NROWS / 4, 256, 0, stream>>>(cdd, his, WT, bias, Y);
    attn_topk_kernel<<<NCDD, 256, 0, stream>>>(Y, mask, idx_ws, w_ws, out + OUT0);
    gather_scale_kernel<<<NCDD * K_ * 4, 256, 0, stream>>>(emb, idx_ws, w_ws, out);
}